// Round 1
// baseline (147.616 us; speedup 1.0000x reference)
//
#include <hip/hip_runtime.h>
#include <math.h>

// ---------------- constants (fp64, folded at compile time) ----------------
#define PI_D   3.14159265358979323846
#define TWO_PI 6.28318530717958647692
#define INV_2PI 0.15915494309189533577
#define K_D    (1.0 / 44100.0)
#define MAX_OM_D (10000.0 * 2.0 * PI_D)
#define LN10   2.30258509299404568402
// ALPHA = 3*ln10/DOMSQ*(OM2^2/TAU0) with DOMSQ==OM2^2  ->  3*ln10/6
#define ALPHA_D (3.0 * LN10 / 6.0)
// BETA = 3*ln10/DOMSQ*(1/TAU1-1/TAU0), OM2 = 2*pi*500
#define OM2_D  (2.0 * PI_D * 500.0)
#define BETA_D (3.0 * LN10 / (OM2_D * OM2_D) * (1.0 / 2.0 - 1.0 / 6.0))

#define NMODES 6400
#define CHUNK  400          // modes per block (16 chunks total)
#define NCHUNK 16
#define TPB    256

__device__ inline double softplus_d(double x) {
    return (x > 0.0) ? x + log1p(exp(-x)) : log1p(exp(x));
}
__device__ inline double sigmoid_d(double x) {
    return 1.0 / (1.0 + exp(-x));
}

// ---------------- kernel 1: per-mode coefficients (fp64) ----------------
__global__ void mode_params_kernel(const float* __restrict__ mu_raw,
                                   const float* __restrict__ Dmu_raw,
                                   const float* __restrict__ Tmu_raw,
                                   const float* __restrict__ Ly_raw,
                                   const float* __restrict__ xo_raw,
                                   const float* __restrict__ yo_raw,
                                   float* __restrict__ coef,
                                   float* __restrict__ decay,
                                   double* __restrict__ phase) {
    int i = blockIdx.x * blockDim.x + threadIdx.x;
    if (i >= NMODES) return;

    double mu  = softplus_d((double)mu_raw[0])  + 1e-4;
    double Dmu = softplus_d((double)Dmu_raw[0]) + 1e-4;
    double Tmu = softplus_d((double)Tmu_raw[0]) + 1e-4;
    double Ly  = 1.1 + (4.0 - 1.1) * ((tanh((double)Ly_raw[0]) + 1.0) * 0.5);
    double xo  = 0.49 + 0.51 * ((tanh((double)xo_raw[0]) + 1.0) * 0.5);   // LX = 1
    double yo  = 0.51 * Ly + 0.49 * Ly * ((tanh((double)yo_raw[0]) + 1.0) * 0.5);
    double xi  = 0.335;          // * LX
    double yi  = 0.467 * Ly;

    int m = i / 80 + 1;
    int n = i % 80 + 1;
    double md = (double)m, nd = (double)n;

    double a  = md * PI_D;            // m*pi/LX
    double b  = nd * PI_D / Ly;       // n*pi/Ly
    double g1 = a * a + b * b;
    double omsq  = Tmu * g1 + Dmu * g1 * g1;
    double omega = sqrt(omsq > 0.0 ? omsq : 0.0);

    double valid = sigmoid_d((MAX_OM_D - omega) * 0.01) *
                   sigmoid_d((omega - 40.0 * PI_D) * 0.01);

    double in_w  = cos(xi * PI_D * md) * cos(yi * PI_D * nd / Ly);
    double out_w = cos(xo * PI_D * md) * cos(yo * PI_D * nd / Ly);
    double sigma = ALPHA_D + BETA_D * omega * omega;
    double ms    = 0.25 * mu * Ly;    // * LX = 1
    double P = out_w * in_w * (K_D * K_D) * exp(-sigma * K_D) / ms * valid;
    double c = P / (sin(omega * K_D) + 1e-8);

    coef[i]  = (float)c;
    decay[i] = (float)(-sigma * K_D);
    phase[i] = omega * K_D;
}

// ---------------- kernel 2: the sinusoid bank (hot loop) ----------------
__global__ __launch_bounds__(TPB) void synth_kernel(const float* __restrict__ coef,
                                                    const float* __restrict__ decay,
                                                    const double* __restrict__ phase,
                                                    float* __restrict__ disp, int T) {
    __shared__ float  s_coef[CHUNK];
    __shared__ float  s_decay[CHUNK];
    __shared__ double s_phase[CHUNK];

    int m0 = blockIdx.y * CHUNK;
    for (int j = threadIdx.x; j < CHUNK; j += blockDim.x) {
        s_coef[j]  = coef[m0 + j];
        s_decay[j] = decay[m0 + j];
        s_phase[j] = phase[m0 + j];
    }
    __syncthreads();

    int t = blockIdx.x * blockDim.x + threadIdx.x;
    if (t >= T) return;

    float  tf  = (float)t;
    double tp1 = (double)(t + 1);
    float  acc = 0.0f;

    #pragma unroll 4
    for (int j = 0; j < CHUNK; ++j) {
        // fp64 argument + range reduction to [-pi, pi], then native sin
        double th = tp1 * s_phase[j];
        double r  = th - TWO_PI * (double)__double2int_rn(th * INV_2PI);
        float  s  = __sinf((float)r);
        float  e  = __expf(s_decay[j] * tf);
        acc = fmaf(s_coef[j] * e, s, acc);
    }
    atomicAdd(&disp[t], acc);
}

// ---------------- kernel 3: first difference + global abs-max ----------------
__global__ void diff_max_kernel(const float* __restrict__ disp,
                                float* __restrict__ out,
                                unsigned int* __restrict__ gmax, int T) {
    __shared__ float smax[TPB];
    int t = blockIdx.x * blockDim.x + threadIdx.x;
    float v = 0.0f;
    if (t < T) {
        float p = (t > 0) ? disp[t - 1] : 0.0f;
        v = (disp[t] - p) * 44100.0f;   // /K ; scale cancels in normalization
        out[t] = v;
    }
    smax[threadIdx.x] = fabsf(v);
    __syncthreads();
    for (int s = TPB / 2; s > 0; s >>= 1) {
        if (threadIdx.x < s)
            smax[threadIdx.x] = fmaxf(smax[threadIdx.x], smax[threadIdx.x + s]);
        __syncthreads();
    }
    if (threadIdx.x == 0)
        atomicMax(gmax, __float_as_uint(smax[0]));  // valid: values are >= 0
}

// ---------------- kernel 4: normalize in place ----------------
__global__ void normalize_kernel(float* __restrict__ out,
                                 const unsigned int* __restrict__ gmax, int T) {
    int t = blockIdx.x * blockDim.x + threadIdx.x;
    if (t >= T) return;
    float mx = __uint_as_float(*gmax);
    out[t] = out[t] / (mx + 1e-8f);
}

extern "C" void kernel_launch(void* const* d_in, const int* in_sizes, int n_in,
                              void* d_out, int out_size, void* d_ws, size_t ws_size,
                              hipStream_t stream) {
    const float* mu_raw  = (const float*)d_in[0];
    const float* Dmu_raw = (const float*)d_in[1];
    const float* Tmu_raw = (const float*)d_in[2];
    const float* Ly_raw  = (const float*)d_in[3];
    const float* xo_raw  = (const float*)d_in[4];
    const float* yo_raw  = (const float*)d_in[5];
    // d_in[6] = num_samples (device); host-side T == out_size
    float* out = (float*)d_out;
    int T = out_size;
    if (T <= 0) return;

    // workspace layout (256B-aligned chunks)
    char* ws = (char*)d_ws;
    float*  coef  = (float*)(ws + 0);            // 25600 B
    float*  decay = (float*)(ws + 25600);        // 25600 B
    double* phase = (double*)(ws + 51200);       // 51200 B  (8B aligned)
    float*  disp  = (float*)(ws + 102400);       // T*4 B
    unsigned int* gmax = (unsigned int*)(ws + 102400 + ((size_t)T * 4 + 255 & ~255ULL));

    // zero accumulator + max (ws is poisoned 0xAA before every call)
    hipMemsetAsync(disp, 0, (size_t)T * sizeof(float), stream);
    hipMemsetAsync(gmax, 0, sizeof(unsigned int), stream);

    mode_params_kernel<<<(NMODES + TPB - 1) / TPB, TPB, 0, stream>>>(
        mu_raw, Dmu_raw, Tmu_raw, Ly_raw, xo_raw, yo_raw, coef, decay, phase);

    dim3 grid((T + TPB - 1) / TPB, NCHUNK);
    synth_kernel<<<grid, TPB, 0, stream>>>(coef, decay, phase, disp, T);

    int nb = (T + TPB - 1) / TPB;
    diff_max_kernel<<<nb, TPB, 0, stream>>>(disp, out, gmax, T);
    normalize_kernel<<<nb, TPB, 0, stream>>>(out, gmax, T);
}

// Round 2
// 145.619 us; speedup vs baseline: 1.0137x; 1.0137x over previous
//
#include <hip/hip_runtime.h>
#include <math.h>

// ---------------- constants (fp64, folded at compile time) ----------------
#define PI_D      3.14159265358979323846
#define K_D       (1.0 / 44100.0)
#define MAX_OM_D  (10000.0 * 2.0 * PI_D)
#define LN10      2.30258509299404568402
// ALPHA = 3*ln10/DOMSQ*(OM2^2/TAU0) with DOMSQ==OM2^2  ->  3*ln10/6
#define ALPHA_D   (3.0 * LN10 / 6.0)
#define OM2_D     (2.0 * PI_D * 500.0)
#define BETA_D    (3.0 * LN10 / (OM2_D * OM2_D) * (1.0 / 2.0 - 1.0 / 6.0))
#define LOG2E_D   1.44269504088896340736
#define INV2PI_D  0.15915494309189533577

#define NMODES 6400
#define CHUNK  400          // modes per block-row (16 chunks total)
#define NCHUNK 16
#define TPB    256
#define FTPB   1024

#if defined(__has_builtin) && __has_builtin(__builtin_amdgcn_sinf)
#define SIN_REV(x) __builtin_amdgcn_sinf(x)        // v_sin_f32: input in revolutions
#else
#define SIN_REV(x) __sinf((x) * 6.28318530717958647692f)
#endif
#if defined(__has_builtin) && __has_builtin(__builtin_amdgcn_exp2f)
#define EXP2F(x) __builtin_amdgcn_exp2f(x)         // v_exp_f32
#else
#define EXP2F(x) exp2f(x)
#endif

__device__ inline double softplus_d(double x) {
    return (x > 0.0) ? x + log1p(exp(-x)) : log1p(exp(x));
}
__device__ inline double sigmoid_d(double x) {
    return 1.0 / (1.0 + exp(-x));
}

// ------------- kernel 1: per-mode coefficients (fp64) + zero disp -------------
__global__ void mode_params_kernel(const float* __restrict__ mu_raw,
                                   const float* __restrict__ Dmu_raw,
                                   const float* __restrict__ Tmu_raw,
                                   const float* __restrict__ Ly_raw,
                                   const float* __restrict__ xo_raw,
                                   const float* __restrict__ yo_raw,
                                   double* __restrict__ phase64,  // omega*K/2pi (revs/sample)
                                   float4* __restrict__ pd,       // {phase32, decay2, coef, 0}
                                   float* __restrict__ disp, int T) {
    int i = blockIdx.x * blockDim.x + threadIdx.x;

    // zero the accumulator (ws is poisoned 0xAA before every call)
    for (int k = i; k < T; k += gridDim.x * blockDim.x) disp[k] = 0.0f;

    if (i >= NMODES) return;

    double mu  = softplus_d((double)mu_raw[0])  + 1e-4;
    double Dmu = softplus_d((double)Dmu_raw[0]) + 1e-4;
    double Tmu = softplus_d((double)Tmu_raw[0]) + 1e-4;
    double Ly  = 1.1 + (4.0 - 1.1) * ((tanh((double)Ly_raw[0]) + 1.0) * 0.5);
    double xo  = 0.49 + 0.51 * ((tanh((double)xo_raw[0]) + 1.0) * 0.5);   // LX = 1
    double yo  = 0.51 * Ly + 0.49 * Ly * ((tanh((double)yo_raw[0]) + 1.0) * 0.5);
    double xi  = 0.335;          // * LX
    double yi  = 0.467 * Ly;

    int m = i / 80 + 1;
    int n = i % 80 + 1;
    double md = (double)m, nd = (double)n;

    double a  = md * PI_D;            // m*pi/LX
    double b  = nd * PI_D / Ly;       // n*pi/Ly
    double g1 = a * a + b * b;
    double omsq  = Tmu * g1 + Dmu * g1 * g1;
    double omega = sqrt(omsq > 0.0 ? omsq : 0.0);

    double valid = sigmoid_d((MAX_OM_D - omega) * 0.01) *
                   sigmoid_d((omega - 40.0 * PI_D) * 0.01);

    double in_w  = cos(xi * PI_D * md) * cos(yi * PI_D * nd / Ly);
    double out_w = cos(xo * PI_D * md) * cos(yo * PI_D * nd / Ly);
    double sigma = ALPHA_D + BETA_D * omega * omega;
    double ms    = 0.25 * mu * Ly;    // * LX = 1
    double P = out_w * in_w * (K_D * K_D) * exp(-sigma * K_D) / ms * valid;
    double c = P / (sin(omega * K_D) + 1e-8);

    double ph_rev = omega * K_D * INV2PI_D;           // revolutions per sample
    phase64[i] = ph_rev;
    pd[i] = make_float4((float)ph_rev,
                        (float)(-sigma * K_D * LOG2E_D),   // decay2: env = 2^(decay2*t)
                        (float)c, 0.0f);
}

// ------------- kernel 2: sinusoid bank, pure fp32 hot loop -------------
__global__ __launch_bounds__(TPB) void synth_kernel(const double* __restrict__ phase64,
                                                    const float4* __restrict__ pd,
                                                    float* __restrict__ disp, int T) {
    __shared__ float2 s_bc[CHUNK];    // {base_rev, cb} per mode for this time-block

    const int m0 = blockIdx.y * CHUNK;
    const int t0 = blockIdx.x * TPB;
    const float t0f = (float)t0;

    // staging: fp64 phase reduction + envelope advance, once per (mode, block)
    for (int j = threadIdx.x; j < CHUNK; j += TPB) {
        double th0 = phase64[m0 + j] * (double)t0;     // revs at local t=0
        float4 p   = pd[m0 + j];
        float base = (float)(th0 - floor(th0));
        float cb   = p.z * EXP2F(p.y * t0f);           // coef * env(t0); underflows to 0 when dead
        s_bc[j] = make_float2(base, cb);
    }
    __syncthreads();

    int t = t0 + threadIdx.x;
    if (t >= T) return;

    const float tp1 = (float)(threadIdx.x + 1);
    const float tf  = (float)threadIdx.x;
    float acc = 0.0f;

    #pragma unroll 4
    for (int j = 0; j < CHUNK; ++j) {
        float2 bc = s_bc[j];                  // broadcast ds_read_b64
        if (bc.y != 0.0f) {                   // wave-uniform: skip decayed modes
            float4 p  = pd[m0 + j];           // uniform address -> scalar load
            float th  = fmaf(tp1, p.x, bc.x); // revolutions, |th| < 60
            th        = th - floorf(th);      // into v_sin_f32 safe domain
            float sn  = SIN_REV(th);
            float e   = EXP2F(p.y * tf);
            acc = fmaf(bc.y * e, sn, acc);
        }
    }
    atomicAdd(&disp[t], acc);
}

// ------------- kernel 3: diff + abs-max + normalize, single block -------------
__global__ __launch_bounds__(FTPB) void finalize_kernel(const float* __restrict__ disp,
                                                        float* __restrict__ out, int T) {
    __shared__ float s_red[FTPB / 64];
    __shared__ float s_gm;
    const int tid = threadIdx.x;

    float lmax = 0.0f;
    for (int t = tid; t < T; t += FTPB) {
        float p = (t > 0) ? disp[t - 1] : 0.0f;
        float v = (disp[t] - p) * 44100.0f;   // == ir (divide by K)
        out[t] = v;
        lmax = fmaxf(lmax, fabsf(v));
    }
    // wave reduce (64 lanes)
    for (int o = 32; o > 0; o >>= 1)
        lmax = fmaxf(lmax, __shfl_down(lmax, o, 64));
    if ((tid & 63) == 0) s_red[tid >> 6] = lmax;
    __syncthreads();
    if (tid == 0) {
        float m = 0.0f;
        for (int i = 0; i < FTPB / 64; ++i) m = fmaxf(m, s_red[i]);
        s_gm = m;
    }
    __syncthreads();
    const float inv = 1.0f / (s_gm + 1e-8f);
    for (int t = tid; t < T; t += FTPB)
        out[t] *= inv;
}

extern "C" void kernel_launch(void* const* d_in, const int* in_sizes, int n_in,
                              void* d_out, int out_size, void* d_ws, size_t ws_size,
                              hipStream_t stream) {
    const float* mu_raw  = (const float*)d_in[0];
    const float* Dmu_raw = (const float*)d_in[1];
    const float* Tmu_raw = (const float*)d_in[2];
    const float* Ly_raw  = (const float*)d_in[3];
    const float* xo_raw  = (const float*)d_in[4];
    const float* yo_raw  = (const float*)d_in[5];
    float* out = (float*)d_out;
    int T = out_size;
    if (T <= 0) return;

    // workspace layout
    char* ws = (char*)d_ws;
    double* phase64 = (double*)(ws + 0);            // 51200 B
    float4* pd      = (float4*)(ws + 51200);        // 102400 B (16B-aligned)
    float*  disp    = (float*)(ws + 153600);        // T*4 B

    int nb1 = ((T > NMODES ? T : NMODES) + TPB - 1) / TPB;
    mode_params_kernel<<<nb1, TPB, 0, stream>>>(
        mu_raw, Dmu_raw, Tmu_raw, Ly_raw, xo_raw, yo_raw, phase64, pd, disp, T);

    dim3 grid((T + TPB - 1) / TPB, NCHUNK);
    synth_kernel<<<grid, TPB, 0, stream>>>(phase64, pd, disp, T);

    finalize_kernel<<<1, FTPB, 0, stream>>>(disp, out, T);
}

// Round 3
// 123.525 us; speedup vs baseline: 1.1950x; 1.1789x over previous
//
#include <hip/hip_runtime.h>
#include <math.h>

// ---------------- constants (fp64, folded at compile time) ----------------
#define PI_D      3.14159265358979323846
#define K_D       (1.0 / 44100.0)
#define MAX_OM_D  (10000.0 * 2.0 * PI_D)
#define LN10      2.30258509299404568402
// ALPHA = 3*ln10/DOMSQ*(OM2^2/TAU0) with DOMSQ==OM2^2  ->  3*ln10/6
#define ALPHA_D   (3.0 * LN10 / 6.0)
#define OM2_D     (2.0 * PI_D * 500.0)
#define BETA_D    (3.0 * LN10 / (OM2_D * OM2_D) * (1.0 / 2.0 - 1.0 / 6.0))
#define LOG2E_D   1.44269504088896340736
#define INV2PI_D  0.15915494309189533577

#define NMODES 6400
#define CHUNK  400          // compacted modes per block-row (16 chunks max)
#define NCHUNK 16
#define TPB    256
#define FTPB   1024

#if defined(__has_builtin) && __has_builtin(__builtin_amdgcn_sinf)
#define SIN_REV(x) __builtin_amdgcn_sinf(x)        // v_sin_f32: input in revolutions
#else
#define SIN_REV(x) __sinf((x) * 6.28318530717958647692f)
#endif
#if defined(__has_builtin) && __has_builtin(__builtin_amdgcn_cosf)
#define COS_REV(x) __builtin_amdgcn_cosf(x)        // v_cos_f32: input in revolutions
#else
#define COS_REV(x) __cosf((x) * 6.28318530717958647692f)
#endif
#if defined(__has_builtin) && __has_builtin(__builtin_amdgcn_exp2f)
#define EXP2F(x) __builtin_amdgcn_exp2f(x)         // v_exp_f32
#else
#define EXP2F(x) exp2f(x)
#endif
#if defined(__has_builtin) && __has_builtin(__builtin_amdgcn_fractf)
#define FRACTF(x) __builtin_amdgcn_fractf(x)       // v_fract_f32
#else
#define FRACTF(x) ((x) - floorf(x))
#endif

__device__ inline double softplus_d(double x) {
    return (x > 0.0) ? x + log1p(exp(-x)) : log1p(exp(x));
}
// cos(2*pi*x), x in fp64 revolutions: fp64 range-reduce -> v_cos_f32
__device__ inline float cosrev_d(double x) {
    return COS_REV((float)(x - floor(x)));
}
__device__ inline float sinrev_d(double x) {
    return SIN_REV((float)(x - floor(x)));
}
// sigmoid via fp32 fast exp (arg computed fp64). Saturates correctly for |x|>88.
__device__ inline float sigmoid_f(double x) {
    return 1.0f / (1.0f + __expf((float)(-x)));
}

// ------- kernel 1: per-mode coefficients (fp64 arith, fp32 trans) + compact + zero disp -------
__global__ void mode_params_kernel(const float* __restrict__ mu_raw,
                                   const float* __restrict__ Dmu_raw,
                                   const float* __restrict__ Tmu_raw,
                                   const float* __restrict__ Ly_raw,
                                   const float* __restrict__ xo_raw,
                                   const float* __restrict__ yo_raw,
                                   double* __restrict__ phase64,  // omega*K/2pi (revs/sample), compacted
                                   float4* __restrict__ pd,       // {phase32, decay2, coef, 0}, compacted
                                   int* __restrict__ cnt,         // active count (pre-zeroed)
                                   float* __restrict__ disp, int T) {
    int i = blockIdx.x * blockDim.x + threadIdx.x;

    // zero the accumulator (ws is poisoned 0xAA before every call)
    for (int k = i; k < T; k += gridDim.x * blockDim.x) disp[k] = 0.0f;

    if (i >= NMODES) return;

    // scalar parameter transforms (few fp64 libm calls, wave-parallel)
    double mu  = softplus_d((double)mu_raw[0])  + 1e-4;
    double Dmu = softplus_d((double)Dmu_raw[0]) + 1e-4;
    double Tmu = softplus_d((double)Tmu_raw[0]) + 1e-4;
    double Ly  = 1.1 + (4.0 - 1.1) * ((tanh((double)Ly_raw[0]) + 1.0) * 0.5);
    double xo  = 0.49 + 0.51 * ((tanh((double)xo_raw[0]) + 1.0) * 0.5);   // LX = 1
    double yoL = 0.51 + 0.49 * ((tanh((double)yo_raw[0]) + 1.0) * 0.5);   // yo / Ly

    int m = i / 80 + 1;
    int n = i % 80 + 1;
    double md = (double)m, nd = (double)n;

    double a  = md * PI_D;            // m*pi/LX
    double b  = nd * PI_D / Ly;       // n*pi/Ly
    double g1 = a * a + b * b;
    double omsq  = Tmu * g1 + Dmu * g1 * g1;
    double omega = sqrt(omsq > 0.0 ? omsq : 0.0);

    float valid = sigmoid_f((MAX_OM_D - omega) * 0.01) *
                  sigmoid_f((omega - 40.0 * PI_D) * 0.01);

    // in_w = cos(0.335*pi*m) * cos(0.467*pi*n)   [yi/Ly = 0.467 exactly]
    // out_w = cos(xo*pi*m)   * cos((yo/Ly)*pi*n)
    float in_w  = cosrev_d(0.1675 * md) * cosrev_d(0.2335 * nd);
    float out_w = cosrev_d(0.5 * xo * md) * cosrev_d(0.5 * yoL * nd);

    double sigma = ALPHA_D + BETA_D * omega * omega;
    double ms    = 0.25 * mu * Ly;    // * LX = 1
    float envK = __expf((float)(-sigma * K_D));
    float P = out_w * in_w * (float)(K_D * K_D / ms) * envK * valid;
    float snw = sinrev_d(omega * K_D * INV2PI_D);   // sin(omega*K), fp64-reduced
    float c = P / (snw + 1e-8f);

    if (c != 0.0f) {                  // global compaction of live modes
        int idx = atomicAdd(cnt, 1);
        double ph_rev = omega * K_D * INV2PI_D;
        phase64[idx] = ph_rev;
        pd[idx] = make_float4((float)ph_rev,
                              (float)(-sigma * K_D * LOG2E_D),  // decay2: env = 2^(decay2*t)
                              c, 0.0f);
    }
}

// ------------- kernel 2: sinusoid bank, branch-free fp32 hot loop -------------
__global__ __launch_bounds__(TPB) void synth_kernel(const double* __restrict__ phase64,
                                                    const float4* __restrict__ pd,
                                                    const int* __restrict__ cnt,
                                                    float* __restrict__ disp, int T) {
    __shared__ float4 s_q[CHUNK];    // {base_rev, cb, phase32, decay2} compacted per block
    __shared__ int s_cnt;

    const int A  = *cnt;             // live modes (broadcast load)
    const int m0 = blockIdx.y * CHUNK;
    if (m0 >= A) return;
    const int lim = (A - m0 < CHUNK) ? (A - m0) : CHUNK;

    const int t0 = blockIdx.x * TPB;
    const float t0f = (float)t0;

    if (threadIdx.x == 0) s_cnt = 0;
    __syncthreads();

    // staging: fp64 phase reduction + envelope advance + per-block compaction
    for (int j = threadIdx.x; j < lim; j += TPB) {
        float4 p = pd[m0 + j];
        float cb = p.z * EXP2F(p.y * t0f);        // coef * env(t0); ==0 when decayed dead
        if (cb != 0.0f) {
            double th0 = phase64[m0 + j] * (double)t0;
            float base = (float)(th0 - floor(th0));
            int idx = atomicAdd(&s_cnt, 1);
            s_q[idx] = make_float4(base, cb, p.x, p.y);
        }
    }
    __syncthreads();
    const int n_act = s_cnt;

    int t = t0 + threadIdx.x;
    if (t >= T) return;

    const float tp1 = (float)(threadIdx.x + 1);
    const float tf  = (float)threadIdx.x;
    float acc = 0.0f;

    #pragma unroll 4
    for (int j = 0; j < n_act; ++j) {
        float4 q = s_q[j];                    // single broadcast ds_read_b128
        float th = fmaf(tp1, q.z, q.x);       // revolutions, |th| < 60
        th       = FRACTF(th);                // v_fract_f32
        float sn = SIN_REV(th);
        float e  = EXP2F(q.w * tf);
        acc = fmaf(q.y * e, sn, acc);
    }
    atomicAdd(&disp[t], acc);
}

// ------------- kernel 3: diff + abs-max + normalize, single block -------------
__global__ __launch_bounds__(FTPB) void finalize_kernel(const float* __restrict__ disp,
                                                        float* __restrict__ out, int T) {
    __shared__ float s_red[FTPB / 64];
    __shared__ float s_gm;
    const int tid = threadIdx.x;

    float lmax = 0.0f;
    for (int t = tid; t < T; t += FTPB) {
        float p = (t > 0) ? disp[t - 1] : 0.0f;
        float v = (disp[t] - p) * 44100.0f;   // == ir (divide by K)
        out[t] = v;
        lmax = fmaxf(lmax, fabsf(v));
    }
    for (int o = 32; o > 0; o >>= 1)
        lmax = fmaxf(lmax, __shfl_down(lmax, o, 64));
    if ((tid & 63) == 0) s_red[tid >> 6] = lmax;
    __syncthreads();
    if (tid == 0) {
        float mx = 0.0f;
        for (int i = 0; i < FTPB / 64; ++i) mx = fmaxf(mx, s_red[i]);
        s_gm = mx;
    }
    __syncthreads();
    const float inv = 1.0f / (s_gm + 1e-8f);
    for (int t = tid; t < T; t += FTPB)
        out[t] *= inv;
}

extern "C" void kernel_launch(void* const* d_in, const int* in_sizes, int n_in,
                              void* d_out, int out_size, void* d_ws, size_t ws_size,
                              hipStream_t stream) {
    const float* mu_raw  = (const float*)d_in[0];
    const float* Dmu_raw = (const float*)d_in[1];
    const float* Tmu_raw = (const float*)d_in[2];
    const float* Ly_raw  = (const float*)d_in[3];
    const float* xo_raw  = (const float*)d_in[4];
    const float* yo_raw  = (const float*)d_in[5];
    float* out = (float*)d_out;
    int T = out_size;
    if (T <= 0) return;

    // workspace layout
    char* ws = (char*)d_ws;
    double* phase64 = (double*)(ws + 0);            // 51200 B
    float4* pd      = (float4*)(ws + 51200);        // 102400 B (16B-aligned)
    int*    cnt     = (int*)(ws + 153600);          // 4 B (+pad to 256)
    float*  disp    = (float*)(ws + 153856);        // T*4 B

    hipMemsetAsync(cnt, 0, sizeof(int), stream);

    int nb1 = ((T > NMODES ? T : NMODES) + TPB - 1) / TPB;
    mode_params_kernel<<<nb1, TPB, 0, stream>>>(
        mu_raw, Dmu_raw, Tmu_raw, Ly_raw, xo_raw, yo_raw, phase64, pd, cnt, disp, T);

    dim3 grid((T + TPB - 1) / TPB, NCHUNK);
    synth_kernel<<<grid, TPB, 0, stream>>>(phase64, pd, cnt, disp, T);

    finalize_kernel<<<1, FTPB, 0, stream>>>(disp, out, T);
}